// Round 3
// baseline (1537.346 us; speedup 1.0000x reference)
//
#include <hip/hip_runtime.h>
#include <math.h>

#define NN 50000
#define EE 800000
#define RR 8
#define SLOPE 0.2f
#define SEGS (NN * RR)            /* 400000 per-(node,relation) segments */
#define NBLK ((SEGS + 255) / 256) /* 1563 scan blocks */

__device__ __forceinline__ float leaky(float v) { return v >= 0.f ? v : SLOPE * v; }

// ============================ CSR build ============================
__global__ void k_count2(const int* __restrict__ dst, const int* __restrict__ et,
                         int* __restrict__ cnt2) {
    int e = blockIdx.x * 256 + threadIdx.x;
    if (e < EE) atomicAdd(&cnt2[dst[e] * RR + et[e]], 1);
}

__global__ void k_scanA(const int* __restrict__ cnt2, int* __restrict__ rp,
                        int* __restrict__ bsum) {
    __shared__ int sh[256];
    int t = threadIdx.x;
    int i = blockIdx.x * 256 + t;
    int v = (i < SEGS) ? cnt2[i] : 0;
    sh[t] = v;
    __syncthreads();
    for (int off = 1; off < 256; off <<= 1) {
        int u = (t >= off) ? sh[t - off] : 0;
        __syncthreads();
        sh[t] += u;
        __syncthreads();
    }
    if (i < SEGS) rp[i] = sh[t] - v;
    if (t == 255) bsum[blockIdx.x] = sh[255];
}

__global__ void k_scanB(int* __restrict__ bsum) {
    __shared__ int sh[256];
    int t = threadIdx.x;
    int loc[8];
    int s = 0;
#pragma unroll
    for (int i = 0; i < 8; i++) {
        int idx = t * 8 + i;
        int v = (idx < NBLK) ? bsum[idx] : 0;
        loc[i] = v;
        s += v;
    }
    sh[t] = s;
    __syncthreads();
    for (int off = 1; off < 256; off <<= 1) {
        int u = (t >= off) ? sh[t - off] : 0;
        __syncthreads();
        sh[t] += u;
        __syncthreads();
    }
    int run = sh[t] - s;
#pragma unroll
    for (int i = 0; i < 8; i++) {
        int idx = t * 8 + i;
        if (idx < NBLK) {
            int v = loc[i];
            bsum[idx] = run;
            run += v;
        }
    }
}

__global__ void k_scanC(int* __restrict__ rp, const int* __restrict__ bsum,
                        int* __restrict__ wo) {
    int i = blockIdx.x * 256 + threadIdx.x;
    if (i < SEGS) {
        int v = rp[i] + bsum[blockIdx.x];
        rp[i] = v;
        wo[i] = v;
    }
    if (i == 0) rp[SEGS] = EE;
}

__global__ void k_fill(const int* __restrict__ src, const int* __restrict__ dst,
                       const int* __restrict__ et, int* __restrict__ wo,
                       int* __restrict__ srcs) {
    int e = blockIdx.x * 256 + threadIdx.x;
    if (e >= EE) return;
    int seg = dst[e] * RR + et[e];
    int pos = atomicAdd(&wo[seg], 1);
    srcs[pos] = src[e];
}

// ============ compose W_r = sum_b comp[r,b] * basis[b] (both layers) ============
__global__ void k_weights(const float* __restrict__ basis1, const float* __restrict__ comp1,
                          const float* __restrict__ basis2, const float* __restrict__ comp2,
                          float* __restrict__ W1, float* __restrict__ W2) {
    int idx = blockIdx.x * 256 + threadIdx.x;
    if (idx < RR * 64 * 64) {
        int r = idx >> 12, io = idx & 4095;
        float acc = 0.f;
#pragma unroll
        for (int b = 0; b < 4; b++) acc += comp1[r * 4 + b] * basis1[b * 4096 + io];
        W1[idx] = acc;
    } else if (idx < 2 * RR * 64 * 64) {
        int j = idx - RR * 64 * 64;
        int r = j >> 12, io = j & 4095;
        float acc = 0.f;
#pragma unroll
        for (int b = 0; b < 4; b++) acc += comp2[r * 4 + b] * basis2[b * 4096 + io];
        W2[j] = acc;
    }
}

// ================= fused RGCN layer 1: 64 -> 64, +root+bias+relu =================
// wave owns 8 nodes; lane = output channel o; mean via register gather,
// matvec via __shfl broadcast; W read from global (L2-resident, amortized x8).
__global__ __launch_bounds__(256) void k_rgcn1f(
        const int* __restrict__ rp, const int* __restrict__ srcs,
        const float* __restrict__ X, const float* __restrict__ W,
        const float* __restrict__ root, const float* __restrict__ bias,
        float* __restrict__ Y) {
    int wid = threadIdx.x >> 6, lane = threadIdx.x & 63;
    int g = blockIdx.x * 4 + wid;
    int n0 = g * 8;
    if (n0 >= NN) return;
    float acc[8];
#pragma unroll
    for (int j = 0; j < 8; j++) acc[j] = bias[lane];
    // root term: mean := x[n]
    {
        float m[8];
#pragma unroll
        for (int j = 0; j < 8; j++) {
            int n = n0 + j;
            m[j] = (n < NN) ? X[(size_t)n * 64 + lane] : 0.f;
        }
#pragma unroll 16
        for (int i = 0; i < 64; i++) {
            float w = root[i * 64 + lane];
#pragma unroll
            for (int j = 0; j < 8; j++) acc[j] += __shfl(m[j], i) * w;
        }
    }
    for (int r = 0; r < RR; r++) {
        float m[8];
#pragma unroll
        for (int j = 0; j < 8; j++) {
            int n = n0 + j;
            float s0 = 0.f;
            int cnt = 0;
            if (n < NN) {
                int beg = rp[n * RR + r], end = rp[n * RR + r + 1];
                cnt = end - beg;
                for (int k = beg; k < end; k++) s0 += X[(size_t)srcs[k] * 64 + lane];
            }
            m[j] = s0 * (1.f / (float)(cnt > 0 ? cnt : 1));
        }
        const float* Wr = W + r * 4096;
#pragma unroll 16
        for (int i = 0; i < 64; i++) {
            float w = Wr[i * 64 + lane];
#pragma unroll
            for (int j = 0; j < 8; j++) acc[j] += __shfl(m[j], i) * w;
        }
    }
#pragma unroll
    for (int j = 0; j < 8; j++) {
        int n = n0 + j;
        if (n < NN) Y[(size_t)n * 64 + lane] = fmaxf(acc[j], 0.f);
    }
}

// ================= fused RGCN layer 2: 128 -> 32, +root+bias+relu =================
// split-half: lanes 0-31 handle input rows 0..63, lanes 32-63 rows 64..127;
// o = lane&31; final cross-half shfl_xor(32) reduce.
__global__ __launch_bounds__(256) void k_rgcn2f(
        const int* __restrict__ rp, const int* __restrict__ srcs,
        const float* __restrict__ X, const float* __restrict__ W,
        const float* __restrict__ root, const float* __restrict__ bias,
        float* __restrict__ Y) {
    int wid = threadIdx.x >> 6, lane = threadIdx.x & 63;
    int g = blockIdx.x * 4 + wid;
    int n0 = g * 8;
    if (n0 >= NN) return;
    const int ih = lane >> 5, ol = lane & 31;
    const int gbase = ih * 64 + ol;   // gather channel base: mA -> +0, mB -> +32
    const int sl = ih * 32;           // shfl source-lane base
    const int wb = ih * 2048 + ol;    // W row-block base
    float acc[8];
#pragma unroll
    for (int j = 0; j < 8; j++) acc[j] = 0.f;
    // root term
    {
        float mA[8], mB[8];
#pragma unroll
        for (int j = 0; j < 8; j++) {
            int n = n0 + j;
            mA[j] = (n < NN) ? X[(size_t)n * 128 + gbase] : 0.f;
            mB[j] = (n < NN) ? X[(size_t)n * 128 + gbase + 32] : 0.f;
        }
#pragma unroll 8
        for (int i = 0; i < 64; i++) {
            float w = root[wb + i * 32];
#pragma unroll
            for (int j = 0; j < 8; j++) {
                float v = (i < 32) ? __shfl(mA[j], sl + (i & 31)) : __shfl(mB[j], sl + (i & 31));
                acc[j] += v * w;
            }
        }
    }
    for (int r = 0; r < RR; r++) {
        float mA[8], mB[8];
#pragma unroll
        for (int j = 0; j < 8; j++) {
            int n = n0 + j;
            float a = 0.f, b = 0.f;
            int cnt = 0;
            if (n < NN) {
                int beg = rp[n * RR + r], end = rp[n * RR + r + 1];
                cnt = end - beg;
                for (int k = beg; k < end; k++) {
                    const float* xs = X + (size_t)srcs[k] * 128;
                    a += xs[gbase];
                    b += xs[gbase + 32];
                }
            }
            float inv = 1.f / (float)(cnt > 0 ? cnt : 1);
            mA[j] = a * inv;
            mB[j] = b * inv;
        }
        const float* Wr = W + r * 4096;
#pragma unroll 8
        for (int i = 0; i < 64; i++) {
            float w = Wr[wb + i * 32];
#pragma unroll
            for (int j = 0; j < 8; j++) {
                float v = (i < 32) ? __shfl(mA[j], sl + (i & 31)) : __shfl(mB[j], sl + (i & 31));
                acc[j] += v * w;
            }
        }
    }
#pragma unroll
    for (int j = 0; j < 8; j++) {
        acc[j] += __shfl_xor(acc[j], 32);
        int n = n0 + j;
        if (ih == 0 && n < NN) Y[(size_t)n * 32 + ol] = fmaxf(acc[j] + bias[ol], 0.f);
    }
}

// ============ dense projection Y[N,OUT] = X[N,IN] @ W[IN,OUT] (no bias) ============
template <int IN, int OUT>
__global__ __launch_bounds__(256) void k_dense(const float* __restrict__ X,
                                               const float* __restrict__ W,
                                               float* __restrict__ Y) {
    int wid = threadIdx.x >> 6, lane = threadIdx.x & 63;
    int g = blockIdx.x * 4 + wid;
    int n0 = g * 8;
    if (n0 >= NN) return;
    constexpr int NO = OUT / 64;  // 1 or 2 output regs per node
    float m[8];
#pragma unroll
    for (int j = 0; j < 8; j++) {
        int n = n0 + j;
        m[j] = (n < NN && (IN == 64 || lane < IN)) ? X[(size_t)n * IN + (lane % IN)] : 0.f;
    }
    float acc[8][NO];
#pragma unroll
    for (int j = 0; j < 8; j++)
#pragma unroll
        for (int q = 0; q < NO; q++) acc[j][q] = 0.f;
#pragma unroll 16
    for (int i = 0; i < IN; i++) {
        float w[NO];
#pragma unroll
        for (int q = 0; q < NO; q++) w[q] = W[i * OUT + q * 64 + lane];
#pragma unroll
        for (int j = 0; j < 8; j++) {
            float v = __shfl(m[j], i);
#pragma unroll
            for (int q = 0; q < NO; q++) acc[j][q] += v * w[q];
        }
    }
#pragma unroll
    for (int j = 0; j < 8; j++) {
        int n = n0 + j;
        if (n < NN) {
#pragma unroll
            for (int q = 0; q < NO; q++) Y[(size_t)n * OUT + q * 64 + lane] = acc[j][q];
        }
    }
}

// ===================== attention logits =====================
__global__ void k_gat_al(const float* __restrict__ h, const float* __restrict__ a_src,
                         const float* __restrict__ a_dst, float* __restrict__ als,
                         float* __restrict__ ald, int C) {
    int i = blockIdx.x * 256 + threadIdx.x;  // i = n*4 + hh
    if (i >= NN * 4) return;
    int hh = i & 3;
    const float* hp = h + (size_t)i * C;
    float a = 0.f, b = 0.f;
    for (int c = 0; c < C; c++) {
        float v = hp[c];
        a += v * a_src[hh * C + c];
        b += v * a_dst[hh * C + c];
    }
    als[i] = a;
    ald[i] = b;
}

// ===================== fused per-dst GAT, ONE pass (no max; logits are O(1)) =====================
template <int HC, int C, bool MEANOUT>
__global__ void k_gat(const int* __restrict__ rp, const int* __restrict__ srcs,
                      const float* __restrict__ als, const float* __restrict__ ald,
                      const float* __restrict__ h, const float* __restrict__ bias,
                      float* __restrict__ out) {
    int wid = threadIdx.x >> 6, lane = threadIdx.x & 63;
    int n = blockIdx.x * 4 + wid;
    if (n >= NN) return;
    constexpr bool TWO = (HC == 128);
    const int hh0 = lane / C;
    const int hh1 = TWO ? (2 + lane / C) : 0;
    float aldd0 = ald[n * 4 + hh0];
    float z0 = __expf(leaky(als[n * 4 + hh0] + aldd0));
    float acc0 = z0 * h[(size_t)n * HC + lane];
    float aldd1 = 0.f, z1 = 0.f, acc1 = 0.f;
    if (TWO) {
        aldd1 = ald[n * 4 + hh1];
        z1 = __expf(leaky(als[n * 4 + hh1] + aldd1));
        acc1 = z1 * h[(size_t)n * HC + 64 + lane];
    }
    int beg = rp[n * RR], end = rp[n * RR + RR];
    for (int k = beg; k < end; k++) {
        int s = srcs[k];
        float p0 = __expf(leaky(als[s * 4 + hh0] + aldd0));
        z0 += p0;
        acc0 += p0 * h[(size_t)s * HC + lane];
        if (TWO) {
            float p1 = __expf(leaky(als[s * 4 + hh1] + aldd1));
            z1 += p1;
            acc1 += p1 * h[(size_t)s * HC + 64 + lane];
        }
    }
    if (!MEANOUT) {
        out[(size_t)n * HC + lane] = acc0 / z0 + bias[lane];
        if (TWO) out[(size_t)n * HC + 64 + lane] = acc1 / z1 + bias[64 + lane];
    } else {
        float v = acc0 / z0;  // lane = hh*16 + c; sum 4 heads per channel
        v += __shfl_xor(v, 16);
        v += __shfl_xor(v, 32);
        if (lane < 16) {
            float o2 = 0.25f * v + bias[lane];
            o2 = fmaxf(o2, 0.f);
            out[n * 16 + lane] = tanhf(o2);
        }
    }
}

extern "C" void kernel_launch(void* const* d_in, const int* in_sizes, int n_in,
                              void* d_out, int out_size, void* d_ws, size_t ws_size,
                              hipStream_t stream) {
    const float* x      = (const float*)d_in[0];
    const int*   ei     = (const int*)d_in[1];
    const int*   et     = (const int*)d_in[2];
    const float* basis1 = (const float*)d_in[3];
    const float* comp1  = (const float*)d_in[4];
    const float* root1  = (const float*)d_in[5];
    const float* brg1   = (const float*)d_in[6];
    const float* wg1    = (const float*)d_in[7];
    const float* asrc1  = (const float*)d_in[8];
    const float* adst1  = (const float*)d_in[9];
    const float* bg1    = (const float*)d_in[10];
    const float* basis2 = (const float*)d_in[11];
    const float* comp2  = (const float*)d_in[12];
    const float* root2  = (const float*)d_in[13];
    const float* brg2   = (const float*)d_in[14];
    const float* wg2    = (const float*)d_in[15];
    const float* asrc2  = (const float*)d_in[16];
    const float* adst2  = (const float*)d_in[17];
    const float* bg2    = (const float*)d_in[18];
    const int* src = ei;
    const int* dst = ei + EE;
    float* out = (float*)d_out;

    // ---- workspace layout ----
    int* wsi = (int*)d_ws;
    size_t ioff = 0;
    auto ialloc = [&](size_t n) { int* p = wsi + ioff; ioff += (n + 3) & ~(size_t)3; return p; };
    int* cnt2 = ialloc(SEGS);
    int* rp   = ialloc(SEGS + 1);
    int* wo   = ialloc(SEGS + 1);
    int* bsum = ialloc(2048);
    int* srcs = ialloc(EE);
    float* wsf = (float*)(wsi + ioff);
    size_t foff = 0;
    auto falloc = [&](size_t n) { float* p = wsf + foff; foff += (n + 3) & ~(size_t)3; return p; };
    float* W1   = falloc(RR * 64 * 64);
    float* W2   = falloc(RR * 128 * 32);
    float* h1   = falloc((size_t)NN * 128);  // also GAT1 input
    float* x1   = falloc((size_t)NN * 64);
    float* x2   = falloc((size_t)NN * 128);
    float* x3   = falloc((size_t)NN * 32);
    float* h2   = falloc((size_t)NN * 64);
    float* als  = falloc((size_t)NN * 4);
    float* ald  = falloc((size_t)NN * 4);
    if (ws_size < (ioff * sizeof(int) + foff * sizeof(float))) return;

    const int EB = (EE + 255) / 256;
    const int NB4 = (NN + 3) / 4;              // wave-per-node kernels
    const int NB32 = (NN + 31) / 32;           // wave-per-8-nodes kernels (4 waves/block)

    // ---- CSR build (dst,relation)-sorted ----
    hipMemsetAsync(cnt2, 0, SEGS * sizeof(int), stream);
    k_count2<<<EB, 256, 0, stream>>>(dst, et, cnt2);
    k_scanA<<<NBLK, 256, 0, stream>>>(cnt2, rp, bsum);
    k_scanB<<<1, 256, 0, stream>>>(bsum);
    k_scanC<<<NBLK, 256, 0, stream>>>(rp, bsum, wo);
    k_fill<<<EB, 256, 0, stream>>>(src, dst, et, wo, srcs);
    k_weights<<<(2 * RR * 64 * 64) / 256, 256, 0, stream>>>(basis1, comp1, basis2, comp2, W1, W2);

    // ---- layer 1: RGCN(64->64) + relu (fully fused) ----
    k_rgcn1f<<<NB32, 256, 0, stream>>>(rp, srcs, x, W1, root1, brg1, x1);

    // ---- layer 2: GAT(64 -> 4x32 concat) ----
    k_dense<64, 128><<<NB32, 256, 0, stream>>>(x1, wg1, h1);
    k_gat_al<<<(NN * 4 + 255) / 256, 256, 0, stream>>>(h1, asrc1, adst1, als, ald, 32);
    k_gat<128, 32, false><<<NB4, 256, 0, stream>>>(rp, srcs, als, ald, h1, bg1, x2);

    // ---- layer 3: RGCN(128->32) + relu (fully fused) ----
    k_rgcn2f<<<NB32, 256, 0, stream>>>(rp, srcs, x2, W2, root2, brg2, x3);

    // ---- layer 4: GAT(32 -> 4x16, mean heads) + relu + tanh ----
    k_dense<32, 64><<<NB32, 256, 0, stream>>>(x3, wg2, h2);
    k_gat_al<<<(NN * 4 + 255) / 256, 256, 0, stream>>>(h2, asrc2, adst2, als, ald, 16);
    k_gat<64, 16, true><<<NB4, 256, 0, stream>>>(rp, srcs, als, ald, h2, bg2, out);
}

// Round 4
// 1150.328 us; speedup vs baseline: 1.3364x; 1.3364x over previous
//
#include <hip/hip_runtime.h>
#include <math.h>

#define NN 50000
#define EE 800000
#define RR 8
#define SLOPE 0.2f
#define SEGS (NN * RR)            /* 400000 per-(node,relation) segments */
#define NBLK ((SEGS + 255) / 256) /* 1563 scan blocks */

__device__ __forceinline__ float leaky(float v) { return v >= 0.f ? v : SLOPE * v; }

// ============================ CSR build ============================
__global__ void k_count2(const int* __restrict__ dst, const int* __restrict__ et,
                         int* __restrict__ cnt2) {
    int e = blockIdx.x * 256 + threadIdx.x;
    if (e < EE) atomicAdd(&cnt2[dst[e] * RR + et[e]], 1);
}

__global__ void k_scanA(const int* __restrict__ cnt2, int* __restrict__ rp,
                        int* __restrict__ bsum) {
    __shared__ int sh[256];
    int t = threadIdx.x;
    int i = blockIdx.x * 256 + t;
    int v = (i < SEGS) ? cnt2[i] : 0;
    sh[t] = v;
    __syncthreads();
    for (int off = 1; off < 256; off <<= 1) {
        int u = (t >= off) ? sh[t - off] : 0;
        __syncthreads();
        sh[t] += u;
        __syncthreads();
    }
    if (i < SEGS) rp[i] = sh[t] - v;
    if (t == 255) bsum[blockIdx.x] = sh[255];
}

__global__ void k_scanB(int* __restrict__ bsum) {
    __shared__ int sh[256];
    int t = threadIdx.x;
    int loc[8];
    int s = 0;
#pragma unroll
    for (int i = 0; i < 8; i++) {
        int idx = t * 8 + i;
        int v = (idx < NBLK) ? bsum[idx] : 0;
        loc[i] = v;
        s += v;
    }
    sh[t] = s;
    __syncthreads();
    for (int off = 1; off < 256; off <<= 1) {
        int u = (t >= off) ? sh[t - off] : 0;
        __syncthreads();
        sh[t] += u;
        __syncthreads();
    }
    int run = sh[t] - s;
#pragma unroll
    for (int i = 0; i < 8; i++) {
        int idx = t * 8 + i;
        if (idx < NBLK) {
            int v = loc[i];
            bsum[idx] = run;
            run += v;
        }
    }
}

__global__ void k_scanC(int* __restrict__ rp, const int* __restrict__ bsum,
                        int* __restrict__ wo) {
    int i = blockIdx.x * 256 + threadIdx.x;
    if (i < SEGS) {
        int v = rp[i] + bsum[blockIdx.x];
        rp[i] = v;
        wo[i] = v;
    }
    if (i == 0) rp[SEGS] = EE;
}

__global__ void k_fill(const int* __restrict__ src, const int* __restrict__ dst,
                       const int* __restrict__ et, int* __restrict__ wo,
                       int* __restrict__ srcs) {
    int e = blockIdx.x * 256 + threadIdx.x;
    if (e >= EE) return;
    int seg = dst[e] * RR + et[e];
    int pos = atomicAdd(&wo[seg], 1);
    srcs[pos] = src[e];
}

// ============ compose W_r = sum_b comp[r,b] * basis[b] (both layers) ============
__global__ void k_weights(const float* __restrict__ basis1, const float* __restrict__ comp1,
                          const float* __restrict__ basis2, const float* __restrict__ comp2,
                          float* __restrict__ W1, float* __restrict__ W2) {
    int idx = blockIdx.x * 256 + threadIdx.x;
    if (idx < RR * 64 * 64) {
        int r = idx >> 12, io = idx & 4095;
        float acc = 0.f;
#pragma unroll
        for (int b = 0; b < 4; b++) acc += comp1[r * 4 + b] * basis1[b * 4096 + io];
        W1[idx] = acc;
    } else if (idx < 2 * RR * 64 * 64) {
        int j = idx - RR * 64 * 64;
        int r = j >> 12, io = j & 4095;
        float acc = 0.f;
#pragma unroll
        for (int b = 0; b < 4; b++) acc += comp2[r * 4 + b] * basis2[b * 4096 + io];
        W2[j] = acc;
    }
}

// ================= fused RGCN layer 1: 64 -> 64, +root+bias+relu =================
// block = 512 threads = 8 waves, owns 8 nodes. Wave w handles relation w for all
// 8 nodes (parallel gathers), shfl-matvec with W_w, LDS reduce across waves,
// then wave j does node j's root matvec + bias + relu. No atomics.
__global__ __launch_bounds__(512) void k_rgcn1f(
        const int* __restrict__ rp, const int* __restrict__ srcs,
        const float* __restrict__ X, const float* __restrict__ W,
        const float* __restrict__ root, const float* __restrict__ bias,
        float* __restrict__ Y) {
    __shared__ float red[8 * 8 * 64];  // [wave][node][ch] = 16 KB
    int w = threadIdx.x >> 6, lane = threadIdx.x & 63;
    int n0 = blockIdx.x * 8;  // NN % 8 == 0

    int beg[8], end[8];
#pragma unroll
    for (int j = 0; j < 8; j++) {
        beg[j] = rp[(n0 + j) * RR + w];
        end[j] = rp[(n0 + j) * RR + w + 1];
    }
    float m[8];
#pragma unroll
    for (int j = 0; j < 8; j++) {
        float s = 0.f;
        int k = beg[j];
        for (; k + 2 <= end[j]; k += 2) {
            int sa = srcs[k], sb = srcs[k + 1];
            float va = X[(size_t)sa * 64 + lane];
            float vb = X[(size_t)sb * 64 + lane];
            s += va + vb;
        }
        if (k < end[j]) s += X[(size_t)srcs[k] * 64 + lane];
        int c = end[j] - beg[j];
        m[j] = s * (1.f / (float)(c > 0 ? c : 1));
    }
    float acc[8];
#pragma unroll
    for (int j = 0; j < 8; j++) acc[j] = 0.f;
    const float* Wr = W + w * 4096;
#pragma unroll 16
    for (int i = 0; i < 64; i++) {
        float wv = Wr[i * 64 + lane];
#pragma unroll
        for (int j = 0; j < 8; j++) acc[j] += __shfl(m[j], i) * wv;
    }
#pragma unroll
    for (int j = 0; j < 8; j++) red[w * 512 + j * 64 + lane] = acc[j];
    __syncthreads();
    // epilogue: wave j -> node j
    {
        int j = w, n = n0 + j;
        float r0 = 0.f;
#pragma unroll
        for (int w2 = 0; w2 < 8; w2++) r0 += red[w2 * 512 + j * 64 + lane];
        float xv = X[(size_t)n * 64 + lane];
#pragma unroll 16
        for (int i = 0; i < 64; i++) r0 += __shfl(xv, i) * root[i * 64 + lane];
        Y[(size_t)n * 64 + lane] = fmaxf(r0 + bias[lane], 0.f);
    }
}

// ================= fused RGCN layer 2: 128 -> 32, +root+bias+relu =================
// same structure; split-half: ih=lane>>5 owns input rows ih*64..ih*64+63, ol=lane&31
// is the output channel; halves summed in the LDS reduction.
__global__ __launch_bounds__(512) void k_rgcn2f(
        const int* __restrict__ rp, const int* __restrict__ srcs,
        const float* __restrict__ X, const float* __restrict__ W,
        const float* __restrict__ root, const float* __restrict__ bias,
        float* __restrict__ Y) {
    __shared__ float red[8 * 8 * 64];  // [wave][node][half*32+ol] = 16 KB
    int w = threadIdx.x >> 6, lane = threadIdx.x & 63;
    int n0 = blockIdx.x * 8;
    const int ih = lane >> 5, ol = lane & 31;
    const int gbase = ih * 64 + ol;  // gather channels: mA -> gbase, mB -> gbase+32
    const int sl = ih * 32;          // shfl source-lane base for this half
    const int wb = ih * 2048 + ol;   // W row-block base (row ih*64+i, col ol)

    int beg[8], end[8];
#pragma unroll
    for (int j = 0; j < 8; j++) {
        beg[j] = rp[(n0 + j) * RR + w];
        end[j] = rp[(n0 + j) * RR + w + 1];
    }
    float mA[8], mB[8];
#pragma unroll
    for (int j = 0; j < 8; j++) {
        float a = 0.f, b = 0.f;
        int k = beg[j];
        for (; k + 2 <= end[j]; k += 2) {
            const float* xa = X + (size_t)srcs[k] * 128;
            const float* xb = X + (size_t)srcs[k + 1] * 128;
            float a0 = xa[gbase], b0 = xa[gbase + 32];
            float a1 = xb[gbase], b1 = xb[gbase + 32];
            a += a0 + a1;
            b += b0 + b1;
        }
        if (k < end[j]) {
            const float* xs = X + (size_t)srcs[k] * 128;
            a += xs[gbase];
            b += xs[gbase + 32];
        }
        int c = end[j] - beg[j];
        float inv = 1.f / (float)(c > 0 ? c : 1);
        mA[j] = a * inv;
        mB[j] = b * inv;
    }
    float acc[8];
#pragma unroll
    for (int j = 0; j < 8; j++) acc[j] = 0.f;
    const float* Wr = W + w * 4096;
#pragma unroll 8
    for (int i = 0; i < 64; i++) {
        float wv = Wr[wb + i * 32];
#pragma unroll
        for (int j = 0; j < 8; j++) {
            float v = (i < 32) ? __shfl(mA[j], sl + (i & 31)) : __shfl(mB[j], sl + (i & 31));
            acc[j] += v * wv;
        }
    }
#pragma unroll
    for (int j = 0; j < 8; j++) red[w * 512 + j * 64 + lane] = acc[j];
    __syncthreads();
    // epilogue: wave j -> node j; lanes 0..31 produce the 32 outputs
    {
        int j = w, n = n0 + j;
        float r0 = 0.f;
#pragma unroll
        for (int w2 = 0; w2 < 8; w2++)
            r0 += red[w2 * 512 + j * 64 + ol] + red[w2 * 512 + j * 64 + 32 + ol];
        float xvA = X[(size_t)n * 128 + lane];
        float xvB = X[(size_t)n * 128 + 64 + lane];
#pragma unroll 16
        for (int i = 0; i < 64; i++) r0 += __shfl(xvA, i) * root[i * 32 + ol];
#pragma unroll 16
        for (int i = 0; i < 64; i++) r0 += __shfl(xvB, i) * root[(64 + i) * 32 + ol];
        if (lane < 32) Y[(size_t)n * 32 + ol] = fmaxf(r0 + bias[ol], 0.f);
    }
}

// ============ dense projection Y[N,OUT] = X[N,IN] @ W[IN,OUT] (no bias) ============
template <int IN, int OUT>
__global__ __launch_bounds__(256) void k_dense(const float* __restrict__ X,
                                               const float* __restrict__ W,
                                               float* __restrict__ Y) {
    int wid = threadIdx.x >> 6, lane = threadIdx.x & 63;
    int g = blockIdx.x * 4 + wid;
    int n0 = g * 8;
    if (n0 >= NN) return;
    constexpr int NO = OUT / 64;  // 1 or 2 output regs per node
    float m[8];
#pragma unroll
    for (int j = 0; j < 8; j++) {
        int n = n0 + j;
        m[j] = (n < NN && (IN == 64 || lane < IN)) ? X[(size_t)n * IN + (lane % IN)] : 0.f;
    }
    float acc[8][NO];
#pragma unroll
    for (int j = 0; j < 8; j++)
#pragma unroll
        for (int q = 0; q < NO; q++) acc[j][q] = 0.f;
#pragma unroll 16
    for (int i = 0; i < IN; i++) {
        float wv[NO];
#pragma unroll
        for (int q = 0; q < NO; q++) wv[q] = W[i * OUT + q * 64 + lane];
#pragma unroll
        for (int j = 0; j < 8; j++) {
            float v = __shfl(m[j], i);
#pragma unroll
            for (int q = 0; q < NO; q++) acc[j][q] += v * wv[q];
        }
    }
#pragma unroll
    for (int j = 0; j < 8; j++) {
        int n = n0 + j;
        if (n < NN) {
#pragma unroll
            for (int q = 0; q < NO; q++) Y[(size_t)n * OUT + q * 64 + lane] = acc[j][q];
        }
    }
}

// ===================== attention logits =====================
__global__ void k_gat_al(const float* __restrict__ h, const float* __restrict__ a_src,
                         const float* __restrict__ a_dst, float* __restrict__ als,
                         float* __restrict__ ald, int C) {
    int i = blockIdx.x * 256 + threadIdx.x;  // i = n*4 + hh
    if (i >= NN * 4) return;
    int hh = i & 3;
    const float* hp = h + (size_t)i * C;
    float a = 0.f, b = 0.f;
    for (int c = 0; c < C; c++) {
        float v = hp[c];
        a += v * a_src[hh * C + c];
        b += v * a_dst[hh * C + c];
    }
    als[i] = a;
    ald[i] = b;
}

// ============ fused per-dst GAT, one pass (logits O(1): no max needed), unroll-4 ============
template <int HC, int C, bool MEANOUT>
__global__ __launch_bounds__(256) void k_gat(const int* __restrict__ rp, const int* __restrict__ srcs,
                      const float* __restrict__ als, const float* __restrict__ ald,
                      const float* __restrict__ h, const float* __restrict__ bias,
                      float* __restrict__ out) {
    int wid = threadIdx.x >> 6, lane = threadIdx.x & 63;
    int n = blockIdx.x * 4 + wid;
    if (n >= NN) return;
    constexpr bool TWO = (HC == 128);
    const int hh0 = lane / C;
    const int hh1 = TWO ? (2 + lane / C) : 0;
    float aldd0 = ald[n * 4 + hh0];
    float z0 = __expf(leaky(als[n * 4 + hh0] + aldd0));
    float acc0 = z0 * h[(size_t)n * HC + lane];
    float aldd1 = 0.f, z1 = 0.f, acc1 = 0.f;
    if (TWO) {
        aldd1 = ald[n * 4 + hh1];
        z1 = __expf(leaky(als[n * 4 + hh1] + aldd1));
        acc1 = z1 * h[(size_t)n * HC + 64 + lane];
    }
    int beg = rp[n * RR], end = rp[n * RR + RR];
    int k = beg;
    for (; k + 4 <= end; k += 4) {
        int s[4];
#pragma unroll
        for (int u = 0; u < 4; u++) s[u] = srcs[k + u];
        float q0[4], q1[4], hv0[4], hv1[4];
#pragma unroll
        for (int u = 0; u < 4; u++) q0[u] = als[s[u] * 4 + hh0];
        if (TWO) {
#pragma unroll
            for (int u = 0; u < 4; u++) q1[u] = als[s[u] * 4 + hh1];
        }
#pragma unroll
        for (int u = 0; u < 4; u++) hv0[u] = h[(size_t)s[u] * HC + lane];
        if (TWO) {
#pragma unroll
            for (int u = 0; u < 4; u++) hv1[u] = h[(size_t)s[u] * HC + 64 + lane];
        }
#pragma unroll
        for (int u = 0; u < 4; u++) {
            float p0 = __expf(leaky(q0[u] + aldd0));
            z0 += p0;
            acc0 += p0 * hv0[u];
            if (TWO) {
                float p1 = __expf(leaky(q1[u] + aldd1));
                z1 += p1;
                acc1 += p1 * hv1[u];
            }
        }
    }
    for (; k < end; k++) {
        int s = srcs[k];
        float p0 = __expf(leaky(als[s * 4 + hh0] + aldd0));
        z0 += p0;
        acc0 += p0 * h[(size_t)s * HC + lane];
        if (TWO) {
            float p1 = __expf(leaky(als[s * 4 + hh1] + aldd1));
            z1 += p1;
            acc1 += p1 * h[(size_t)s * HC + 64 + lane];
        }
    }
    if (!MEANOUT) {
        out[(size_t)n * HC + lane] = acc0 / z0 + bias[lane];
        if (TWO) out[(size_t)n * HC + 64 + lane] = acc1 / z1 + bias[64 + lane];
    } else {
        float v = acc0 / z0;  // lane = hh*16 + c; sum 4 heads per channel
        v += __shfl_xor(v, 16);
        v += __shfl_xor(v, 32);
        if (lane < 16) {
            float o2 = 0.25f * v + bias[lane];
            o2 = fmaxf(o2, 0.f);
            out[n * 16 + lane] = tanhf(o2);
        }
    }
}

extern "C" void kernel_launch(void* const* d_in, const int* in_sizes, int n_in,
                              void* d_out, int out_size, void* d_ws, size_t ws_size,
                              hipStream_t stream) {
    const float* x      = (const float*)d_in[0];
    const int*   ei     = (const int*)d_in[1];
    const int*   et     = (const int*)d_in[2];
    const float* basis1 = (const float*)d_in[3];
    const float* comp1  = (const float*)d_in[4];
    const float* root1  = (const float*)d_in[5];
    const float* brg1   = (const float*)d_in[6];
    const float* wg1    = (const float*)d_in[7];
    const float* asrc1  = (const float*)d_in[8];
    const float* adst1  = (const float*)d_in[9];
    const float* bg1    = (const float*)d_in[10];
    const float* basis2 = (const float*)d_in[11];
    const float* comp2  = (const float*)d_in[12];
    const float* root2  = (const float*)d_in[13];
    const float* brg2   = (const float*)d_in[14];
    const float* wg2    = (const float*)d_in[15];
    const float* asrc2  = (const float*)d_in[16];
    const float* adst2  = (const float*)d_in[17];
    const float* bg2    = (const float*)d_in[18];
    const int* src = ei;
    const int* dst = ei + EE;
    float* out = (float*)d_out;

    // ---- workspace layout ----
    int* wsi = (int*)d_ws;
    size_t ioff = 0;
    auto ialloc = [&](size_t n) { int* p = wsi + ioff; ioff += (n + 3) & ~(size_t)3; return p; };
    int* cnt2 = ialloc(SEGS);
    int* rp   = ialloc(SEGS + 1);
    int* wo   = ialloc(SEGS + 1);
    int* bsum = ialloc(2048);
    int* srcs = ialloc(EE);
    float* wsf = (float*)(wsi + ioff);
    size_t foff = 0;
    auto falloc = [&](size_t n) { float* p = wsf + foff; foff += (n + 3) & ~(size_t)3; return p; };
    float* W1   = falloc(RR * 64 * 64);
    float* W2   = falloc(RR * 128 * 32);
    float* h1   = falloc((size_t)NN * 128);
    float* x1   = falloc((size_t)NN * 64);
    float* x2   = falloc((size_t)NN * 128);
    float* x3   = falloc((size_t)NN * 32);
    float* h2   = falloc((size_t)NN * 64);
    float* als  = falloc((size_t)NN * 4);
    float* ald  = falloc((size_t)NN * 4);
    if (ws_size < (ioff * sizeof(int) + foff * sizeof(float))) return;

    const int EB = (EE + 255) / 256;
    const int NB4 = (NN + 3) / 4;    // wave-per-node kernels (256 thr)
    const int NB8 = NN / 8;          // 8-waves-per-8-nodes kernels (512 thr)
    const int NB32 = (NN + 31) / 32; // k_dense (256 thr, 8 nodes/wave)

    // ---- CSR build (dst,relation)-sorted ----
    hipMemsetAsync(cnt2, 0, SEGS * sizeof(int), stream);
    k_count2<<<EB, 256, 0, stream>>>(dst, et, cnt2);
    k_scanA<<<NBLK, 256, 0, stream>>>(cnt2, rp, bsum);
    k_scanB<<<1, 256, 0, stream>>>(bsum);
    k_scanC<<<NBLK, 256, 0, stream>>>(rp, bsum, wo);
    k_fill<<<EB, 256, 0, stream>>>(src, dst, et, wo, srcs);
    k_weights<<<(2 * RR * 64 * 64) / 256, 256, 0, stream>>>(basis1, comp1, basis2, comp2, W1, W2);

    // ---- layer 1: RGCN(64->64) + relu ----
    k_rgcn1f<<<NB8, 512, 0, stream>>>(rp, srcs, x, W1, root1, brg1, x1);

    // ---- layer 2: GAT(64 -> 4x32 concat) ----
    k_dense<64, 128><<<NB32, 256, 0, stream>>>(x1, wg1, h1);
    k_gat_al<<<(NN * 4 + 255) / 256, 256, 0, stream>>>(h1, asrc1, adst1, als, ald, 32);
    k_gat<128, 32, false><<<NB4, 256, 0, stream>>>(rp, srcs, als, ald, h1, bg1, x2);

    // ---- layer 3: RGCN(128->32) + relu ----
    k_rgcn2f<<<NB8, 512, 0, stream>>>(rp, srcs, x2, W2, root2, brg2, x3);

    // ---- layer 4: GAT(32 -> 4x16, mean heads) + relu + tanh ----
    k_dense<32, 64><<<NB32, 256, 0, stream>>>(x3, wg2, h2);
    k_gat_al<<<(NN * 4 + 255) / 256, 256, 0, stream>>>(h2, asrc2, adst2, als, ald, 16);
    k_gat<64, 16, true><<<NB4, 256, 0, stream>>>(rp, srcs, als, ald, h2, bg2, out);
}